// Round 12
// baseline (389.326 us; speedup 1.0000x reference)
//
#include <hip/hip_runtime.h>
#include <math.h>

// ---------------------------------------------------------------------------
// SCN layer, round 12.
//  - No Lh materialization (r11 counters: Lh write stream reached HBM, 238MB W
//    + re-read). rowsum is pure-read; L-GEMM DMA-stages fp32 L directly
//    (global_load_lds, counted vmcnt(8), 64KB LDS, cvt fp32->fp16 at
//    fragment-read, pair-swizzled A slots).
//  - inc-GEMMs + rest: round-8 proven configuration.
// ---------------------------------------------------------------------------

#define EPSV 1e-5f

typedef unsigned short u16;
typedef u16 u16x4 __attribute__((ext_vector_type(4)));
typedef u16 u16x8 __attribute__((ext_vector_type(8)));
typedef float f32x4 __attribute__((ext_vector_type(4)));
typedef _Float16 f16x4 __attribute__((ext_vector_type(4)));
typedef _Float16 f16x8 __attribute__((ext_vector_type(8)));

__device__ inline u16 f2h(float f) {
  union { _Float16 h; u16 u; } c;
  c.h = (_Float16)f;
  return c.u;
}
__device__ inline float h2f(u16 u) {
  union { u16 u; _Float16 h; } c;
  c.u = u;
  return (float)c.h;
}

// ---------------- batched rowsum -> inv (READ-ONLY, wave-per-row, 4 rows/block) --------
__global__ __launch_bounds__(256)
void rowsum_all_k(const float* __restrict__ L0, const float* __restrict__ L1,
                  const float* __restrict__ L2,
                  float* __restrict__ inv0, float* __restrict__ inv1, float* __restrict__ inv2) {
  const int lane = threadIdx.x & 63;
  const int row4 = blockIdx.x * 4 + (threadIdx.x >> 6);
  const float* L; float* inv; int m, r;
  if (row4 < 8192)       { L = L1; inv = inv1; m = 8192; r = row4; }
  else if (row4 < 14336) { L = L2; inv = inv2; m = 6144; r = row4 - 8192; }
  else                   { L = L0; inv = inv0; m = 4096; r = row4 - 14336; }

  const float* row = L + (size_t)r * m;
  float s = 0.f;
  for (int c = lane * 8; c < m; c += 512) {
    float4 a = *reinterpret_cast<const float4*>(row + c);
    float4 d = *reinterpret_cast<const float4*>(row + c + 4);
    s += fabsf(a.x) + fabsf(a.y) + fabsf(a.z) + fabsf(a.w)
       + fabsf(d.x) + fabsf(d.y) + fabsf(d.z) + fabsf(d.w);
  }
  #pragma unroll
  for (int o = 32; o > 0; o >>= 1) s += __shfl_down(s, o, 64);
  if (lane == 0) inv[r] = (s != 0.f) ? rsqrtf(s) : 0.f;
}

// ---------------- batched small GEMM (3 levels): tT[c][r] = fp16((x@W)[r][c]*inv[r]) ----
__global__ __launch_bounds__(256)
void gsmall_all_k(const float* __restrict__ x1, const float* __restrict__ W1,
                  u16* __restrict__ tT1, const float* __restrict__ inv1,
                  const float* __restrict__ x2, const float* __restrict__ W2,
                  u16* __restrict__ tT2, const float* __restrict__ inv2,
                  const float* __restrict__ x0, const float* __restrict__ W0,
                  u16* __restrict__ tT0, const float* __restrict__ inv0)
{
  const int b = blockIdx.x;
  const float *A, *B, *scale; u16* outT; int ldo, rowblk;
  if (b < 256)      { A = x1; B = W1; outT = tT1; scale = inv1; ldo = 8192; rowblk = b * 32; }
  else if (b < 448) { A = x2; B = W2; outT = tT2; scale = inv2; ldo = 6144; rowblk = (b - 256) * 32; }
  else              { A = x0; B = W0; outT = tT0; scale = inv0; ldo = 4096; rowblk = (b - 448) * 32; }

  __shared__ float As[32][36];
  __shared__ float Bs[32][128];
  const int tid = threadIdx.x;

  float acc[4][4];
  #pragma unroll
  for (int i = 0; i < 4; ++i)
    #pragma unroll
    for (int j = 0; j < 4; ++j) acc[i][j] = 0.f;

  const int a_row = tid >> 3, a_col = (tid & 7) * 4;
  const int b_row = tid >> 5, b_col = (tid & 31) * 4;
  const int row0 = (tid >> 5) * 4, col0 = (tid & 31) * 4;

  for (int kk = 0; kk < 128; kk += 32) {
    *reinterpret_cast<float4*>(&As[a_row][a_col]) =
        *reinterpret_cast<const float4*>(A + (size_t)(rowblk + a_row) * 128 + kk + a_col);
    #pragma unroll
    for (int i = 0; i < 4; ++i) {
      int r = b_row + i * 8;
      *reinterpret_cast<float4*>(&Bs[r][b_col]) =
          *reinterpret_cast<const float4*>(B + (size_t)(kk + r) * 128 + b_col);
    }
    __syncthreads();
    #pragma unroll
    for (int k = 0; k < 32; ++k) {
      float4 bb = *reinterpret_cast<const float4*>(&Bs[k][col0]);
      #pragma unroll
      for (int i = 0; i < 4; ++i) {
        float a = As[row0 + i][k];
        acc[i][0] = fmaf(a, bb.x, acc[i][0]);
        acc[i][1] = fmaf(a, bb.y, acc[i][1]);
        acc[i][2] = fmaf(a, bb.z, acc[i][2]);
        acc[i][3] = fmaf(a, bb.w, acc[i][3]);
      }
    }
    __syncthreads();
  }

  const int rb = rowblk + row0;
  float sc[4];
  #pragma unroll
  for (int i = 0; i < 4; ++i) sc[i] = scale[rb + i];
  #pragma unroll
  for (int j = 0; j < 4; ++j) {
    u16x4 p;
    #pragma unroll
    for (int i = 0; i < 4; ++i) p[i] = f2h(acc[i][j] * sc[i]);
    *reinterpret_cast<u16x4*>(outT + (size_t)(col0 + j) * ldo + rb) = p;
  }
}

// ---------------- small GEMM (single level, no scale) for inc prepasses ----------------
__global__ __launch_bounds__(256)
void gemm_small_k(const float* __restrict__ A, const float* __restrict__ B,
                  u16* __restrict__ outT, int ldo)
{
  __shared__ float As[32][36];
  __shared__ float Bs[32][128];
  const int tid = threadIdx.x;
  const int rowblk = blockIdx.x * 32;

  float acc[4][4];
  #pragma unroll
  for (int i = 0; i < 4; ++i)
    #pragma unroll
    for (int j = 0; j < 4; ++j) acc[i][j] = 0.f;

  const int a_row = tid >> 3, a_col = (tid & 7) * 4;
  const int b_row = tid >> 5, b_col = (tid & 31) * 4;
  const int row0 = (tid >> 5) * 4, col0 = (tid & 31) * 4;

  for (int kk = 0; kk < 128; kk += 32) {
    *reinterpret_cast<float4*>(&As[a_row][a_col]) =
        *reinterpret_cast<const float4*>(A + (size_t)(rowblk + a_row) * 128 + kk + a_col);
    #pragma unroll
    for (int i = 0; i < 4; ++i) {
      int r = b_row + i * 8;
      *reinterpret_cast<float4*>(&Bs[r][b_col]) =
          *reinterpret_cast<const float4*>(B + (size_t)(kk + r) * 128 + b_col);
    }
    __syncthreads();
    #pragma unroll
    for (int k = 0; k < 32; ++k) {
      float4 bb = *reinterpret_cast<const float4*>(&Bs[k][col0]);
      #pragma unroll
      for (int i = 0; i < 4; ++i) {
        float a = As[row0 + i][k];
        acc[i][0] = fmaf(a, bb.x, acc[i][0]);
        acc[i][1] = fmaf(a, bb.y, acc[i][1]);
        acc[i][2] = fmaf(a, bb.z, acc[i][2]);
        acc[i][3] = fmaf(a, bb.w, acc[i][3]);
      }
    }
    __syncthreads();
  }

  const int rb = rowblk + row0;
  #pragma unroll
  for (int j = 0; j < 4; ++j) {
    u16x4 p;
    #pragma unroll
    for (int i = 0; i < 4; ++i) p[i] = f2h(acc[i][j]);
    *reinterpret_cast<u16x4*>(outT + (size_t)(col0 + j) * ldo + rb) = p;
  }
}

// ---------------- batched MFMA L-GEMM, DMA-staged fp32 A, counted vmcnt ----------------
// Levels packed: b<1024 lev1(n=K=8192,S=8), <1600 lev2(6144,S=6), else lev0(4096,S=4).
// kchunk=1024 -> nsteps=16. 64-row tile, 4 waves, fp16 partials.
// LDS/buf: A fp32 [64 rows][64 k] @0 (16KB, pair-swizzled 16B slots), B fp16 [128][64] @16K.
__global__ __launch_bounds__(256, 2)
void mfma_dma32_all_k(const float* __restrict__ L1, const u16* __restrict__ tT1, u16* __restrict__ part1,
                      const float* __restrict__ L2, const u16* __restrict__ tT2, u16* __restrict__ part2,
                      const float* __restrict__ L0, const u16* __restrict__ tT0, u16* __restrict__ part0)
{
  __shared__ __align__(16) char smem[2][32768];

  const int tid = threadIdx.x;
  const int b = blockIdx.x;
  const float* A; const u16* Bt; u16* pbase; int n, K, rb, sp;
  if (b < 1024)      { A = L1; Bt = tT1; pbase = part1; n = 8192; K = 8192; rb = b & 127; sp = b >> 7; }
  else if (b < 1600) { int t = b - 1024; A = L2; Bt = tT2; pbase = part2; n = 6144; K = 6144; rb = t % 96; sp = t / 96; }
  else               { int t = b - 1600; A = L0; Bt = tT0; pbase = part0; n = 4096; K = 4096; rb = t & 63; sp = t >> 6; }
  const int rowblk = rb * 64;
  const int k0 = sp * 1024;
  const int nsteps = 16;

  const int l = tid & 63, w = tid >> 6;

  // A staging: instr (w,p) covers rows 16p+4w..+4 (1KB). lane -> row 16p+4w+(l>>4),
  // dest slot acs=l&15; source chunk pair-swizzled so reader finds chunk c at
  // slot ((c>>1)^(r&7))*2+(c&1)  (32B pairs stay contiguous).
  const int arow = 4 * w + (l >> 4);
  const int acs  = l & 15;
  const int agc  = ((((acs >> 1) ^ (arow & 7)) << 1) | (acs & 1));
  const float* gA0 = A + (size_t)(rowblk + arow) * K + k0 + agc * 4;

  // B staging: instr (w,p) covers rows (w+p*4)*8..+8; 8 chunks/row, XOR row&7.
  const int lr8 = l >> 3;
  const int bsc = (l & 7) ^ lr8;
  const u16* gB0 = Bt + (size_t)lr8 * K + k0 + bsc * 8;

#define STAGE(BUF, S)                                                           \
  {                                                                             \
    _Pragma("unroll")                                                           \
    for (int p = 0; p < 4; ++p) {                                               \
      __builtin_amdgcn_global_load_lds(                                         \
          (const __attribute__((address_space(1))) void*)(gA0 + (size_t)p * 16 * K + (S) * 64), \
          (__attribute__((address_space(3))) void*)(&smem[BUF][(16 * p + 4 * w) * 256]), \
          16, 0, 0);                                                            \
    }                                                                           \
    _Pragma("unroll")                                                           \
    for (int p = 0; p < 4; ++p) {                                               \
      const int rbase = (w + p * 4) * 8;                                        \
      __builtin_amdgcn_global_load_lds(                                         \
          (const __attribute__((address_space(1))) void*)(gB0 + (size_t)rbase * K + (S) * 64), \
          (__attribute__((address_space(3))) void*)(&smem[BUF][16384 + rbase * 128]), \
          16, 0, 0);                                                            \
    }                                                                           \
  }

  const int wr = (w >> 1) * 32, wc = (w & 1) * 64;
  const int lrow = l & 15, lks = l >> 4, lsw = l & 7;

  f32x4 acc[2][4];
  #pragma unroll
  for (int mi = 0; mi < 2; ++mi)
    #pragma unroll
    for (int ni = 0; ni < 4; ++ni) acc[mi][ni] = (f32x4){0.f, 0.f, 0.f, 0.f};

  STAGE(0, 0);

  int cur = 0;
  for (int s = 0; s < nsteps; ++s) {
    if (s + 1 < nsteps) {
      STAGE(cur ^ 1, s + 1);                           // 8 more loads in flight
      asm volatile("s_waitcnt vmcnt(8)" ::: "memory"); // stage(s) done; stage(s+1) flies
    } else {
      asm volatile("s_waitcnt vmcnt(0)" ::: "memory");
    }
    asm volatile("s_barrier" ::: "memory");            // all waves: buf[cur] populated
    const char* sA = (const char*)&smem[cur][0];
    const char* sB = (const char*)&smem[cur][16384];
    #pragma unroll
    for (int ks = 0; ks < 2; ++ks) {
      const int fo = ((((ks << 2) | lks) ^ lsw) << 4);
      f16x8 bf[4];
      #pragma unroll
      for (int ni = 0; ni < 4; ++ni)
        bf[ni] = *reinterpret_cast<const f16x8*>(sB + ((wc + ni * 16 + lrow) << 7) + fo);
      #pragma unroll
      for (int mi = 0; mi < 2; ++mi) {
        const int r = wr + mi * 16 + lrow;
        const int pp = ks * 4 + lks;
        const char* ap = sA + r * 256 + ((pp ^ (r & 7)) << 5);
        f32x4 lo = *reinterpret_cast<const f32x4*>(ap);
        f32x4 hi = *reinterpret_cast<const f32x4*>(ap + 16);
        f16x8 af;
        af[0] = (_Float16)lo[0]; af[1] = (_Float16)lo[1];
        af[2] = (_Float16)lo[2]; af[3] = (_Float16)lo[3];
        af[4] = (_Float16)hi[0]; af[5] = (_Float16)hi[1];
        af[6] = (_Float16)hi[2]; af[7] = (_Float16)hi[3];
        #pragma unroll
        for (int ni = 0; ni < 4; ++ni)
          acc[mi][ni] = __builtin_amdgcn_mfma_f32_16x16x32_f16(af, bf[ni], acc[mi][ni], 0, 0, 0);
      }
    }
    asm volatile("s_barrier" ::: "memory");            // buf[cur] free for overwrite
    cur ^= 1;
  }
#undef STAGE

  u16* o = pbase + (size_t)sp * n * 128;
  #pragma unroll
  for (int mi = 0; mi < 2; ++mi)
    #pragma unroll
    for (int ni = 0; ni < 4; ++ni) {
      const int gr = rowblk + wr + mi * 16 + lks * 4;
      const int gc = wc + ni * 16 + lrow;
      f32x4 v = acc[mi][ni];
      #pragma unroll
      for (int q = 0; q < 4; ++q) o[(size_t)(gr + q) * 128 + gc] = f2h(v[q]);
    }
}

// ---------------- MFMA GEMM, reg-staged (A fp32), 64-row tile (inc GEMMs) ----------------
#define LDS_A 0
#define LDS_B 8192
__global__ __launch_bounds__(256, 4)
void mfma_gemm_reg_k(const float* __restrict__ A, int lda,
                     const u16* __restrict__ Bt, int ldb,
                     u16* __restrict__ part,
                     int n, int K, int kchunk)
{
  __shared__ __align__(16) char smem[24576];

  const int tid = threadIdx.x;
  const int rowblk = blockIdx.x * 64;
  const int k0 = blockIdx.y * kchunk;
  const int nsteps = kchunk >> 6;

  const int ar = tid >> 4, acol = (tid & 15) * 4;
  const float* gA = A + (size_t)(rowblk + ar) * lda + k0 + acol;
  const int awb = (ar << 7) + (((((tid & 15) >> 1) ^ (ar & 7)) << 4)) + (tid & 1) * 8;
  const int br = tid >> 3, bc = tid & 7;
  const u16* gB = Bt + (size_t)br * ldb + k0 + bc * 8;
  const int bwb = (br << 7) + (((bc ^ (br & 7)) << 4));

  const int l = tid & 63, w = tid >> 6;
  const int wr = (w >> 1) * 32, wc = (w & 1) * 64;
  const int lrow = l & 15, lks = l >> 4, lsw = l & 7;

  f32x4 acc[2][4];
  #pragma unroll
  for (int mi = 0; mi < 2; ++mi)
    #pragma unroll
    for (int ni = 0; ni < 4; ++ni) acc[mi][ni] = (f32x4){0.f, 0.f, 0.f, 0.f};

  f32x4 ra[4]; u16x8 rbv[4];

#define LOADG(S)                                                              \
  {                                                                           \
    const float* pA = gA + (size_t)(S) * 64;                                  \
    const u16*   pB = gB + (size_t)(S) * 64;                                  \
    _Pragma("unroll")                                                         \
    for (int p = 0; p < 4; ++p) ra[p] = *reinterpret_cast<const f32x4*>(pA + (size_t)p * 16 * lda); \
    _Pragma("unroll")                                                         \
    for (int p = 0; p < 4; ++p) rbv[p] = *reinterpret_cast<const u16x8*>(pB + (size_t)p * 32 * ldb); \
  }

#define STORE_LDS()                                                           \
  {                                                                           \
    _Pragma("unroll")                                                         \
    for (int p = 0; p < 4; ++p) {                                             \
      f16x4 h;                                                                \
      h[0] = (_Float16)ra[p][0]; h[1] = (_Float16)ra[p][1];                   \
      h[2] = (_Float16)ra[p][2]; h[3] = (_Float16)ra[p][3];                   \
      *reinterpret_cast<f16x4*>(smem + LDS_A + awb + p * (16 << 7)) = h;      \
    }                                                                         \
    _Pragma("unroll")                                                         \
    for (int p = 0; p < 4; ++p)                                               \
      *reinterpret_cast<u16x8*>(smem + LDS_B + bwb + p * (32 << 7)) = rbv[p]; \
  }

  LOADG(0);
  STORE_LDS();
  __syncthreads();

  for (int s = 0; s < nsteps; ++s) {
    if (s + 1 < nsteps) LOADG(s + 1);
    #pragma unroll
    for (int ks = 0; ks < 2; ++ks) {
      const int fo = ((((ks << 2) | lks) ^ lsw) << 4);
      f16x8 bf[4];
      #pragma unroll
      for (int ni = 0; ni < 4; ++ni)
        bf[ni] = *reinterpret_cast<const f16x8*>(
            smem + LDS_B + ((wc + ni * 16 + lrow) << 7) + fo);
      #pragma unroll
      for (int mi = 0; mi < 2; ++mi) {
        f16x8 af = *reinterpret_cast<const f16x8*>(
            smem + LDS_A + ((wr + mi * 16 + lrow) << 7) + fo);
        #pragma unroll
        for (int ni = 0; ni < 4; ++ni)
          acc[mi][ni] = __builtin_amdgcn_mfma_f32_16x16x32_f16(af, bf[ni], acc[mi][ni], 0, 0, 0);
      }
    }
    __syncthreads();
    if (s + 1 < nsteps) STORE_LDS();
    __syncthreads();
  }

  u16* o = part + (size_t)blockIdx.y * n * 128;
  #pragma unroll
  for (int mi = 0; mi < 2; ++mi)
    #pragma unroll
    for (int ni = 0; ni < 4; ++ni) {
      const int gr = rowblk + wr + mi * 16 + lks * 4;
      const int gc = wc + ni * 16 + lrow;
      f32x4 v = acc[mi][ni];
      #pragma unroll
      for (int q = 0; q < 4; ++q) o[(size_t)(gr + q) * 128 + gc] = f2h(v[q]);
    }
#undef LOADG
#undef STORE_LDS
}

// ---------------- batched split-K reduce + sigmoid (3 levels) ----------------
__global__ void reduce_sigmoid_all_k(const u16* __restrict__ part1, const u16* __restrict__ part2,
                                     const u16* __restrict__ part0,
                                     const float* __restrict__ inv1, const float* __restrict__ inv2,
                                     const float* __restrict__ inv0,
                                     float* __restrict__ h1, float* __restrict__ out2,
                                     float* __restrict__ h0)
{
  const int i = blockIdx.x * 256 + threadIdx.x;      // u16x8 chunk; 16 per row
  const int row = i >> 4;
  const u16* pb; const float* inv; float* out; int S, lrow; size_t stride;
  if (row < 8192)       { pb = part1; inv = inv1; out = h1;   S = 8; lrow = row;         stride = (size_t)8192 * 128; }
  else if (row < 14336) { pb = part2; inv = inv2; out = out2; S = 6; lrow = row - 8192;  stride = (size_t)6144 * 128; }
  else                  { pb = part0; inv = inv0; out = h0;   S = 4; lrow = row - 14336; stride = (size_t)4096 * 128; }

  const size_t off = (size_t)lrow * 128 + (i & 15) * 8;
  float s[8] = {0.f, 0.f, 0.f, 0.f, 0.f, 0.f, 0.f, 0.f};
  for (int sp = 0; sp < S; ++sp) {
    u16x8 v = *reinterpret_cast<const u16x8*>(pb + (size_t)sp * stride + off);
    #pragma unroll
    for (int j = 0; j < 8; ++j) s[j] += h2f(v[j]);
  }
  const float iv = inv[lrow];
  float4 o0, o1;
  o0.x = 1.f / (1.f + expf(-iv * s[0]));
  o0.y = 1.f / (1.f + expf(-iv * s[1]));
  o0.z = 1.f / (1.f + expf(-iv * s[2]));
  o0.w = 1.f / (1.f + expf(-iv * s[3]));
  o1.x = 1.f / (1.f + expf(-iv * s[4]));
  o1.y = 1.f / (1.f + expf(-iv * s[5]));
  o1.z = 1.f / (1.f + expf(-iv * s[6]));
  o1.w = 1.f / (1.f + expf(-iv * s[7]));
  *reinterpret_cast<float4*>(out + off) = o0;
  *reinterpret_cast<float4*>(out + off + 4) = o1;
}

// ---------------- split-K reduce + add (fp16 partials) ----------------
__global__ void reduce_add_k(const u16* __restrict__ part, int S, size_t stride,
                             const float* __restrict__ h, float* __restrict__ z, int n) {
  int i = blockIdx.x * blockDim.x + threadIdx.x;
  if (i >= n * 16) return;
  size_t off = (size_t)i * 8;
  float s[8] = {0.f, 0.f, 0.f, 0.f, 0.f, 0.f, 0.f, 0.f};
  for (int sp = 0; sp < S; ++sp) {
    u16x8 v = *reinterpret_cast<const u16x8*>(part + (size_t)sp * stride + off);
    #pragma unroll
    for (int j = 0; j < 8; ++j) s[j] += h2f(v[j]);
  }
  float4 h0 = *reinterpret_cast<const float4*>(h + off);
  float4 h1 = *reinterpret_cast<const float4*>(h + off + 4);
  float4 o0 = make_float4(s[0] + h0.x, s[1] + h0.y, s[2] + h0.z, s[3] + h0.w);
  float4 o1 = make_float4(s[4] + h1.x, s[5] + h1.y, s[6] + h1.z, s[7] + h1.w);
  *reinterpret_cast<float4*>(z + off) = o0;
  *reinterpret_cast<float4*>(z + off + 4) = o1;
}

// ---------------- graph norm ----------------
__device__ inline int lbound(const int* __restrict__ b, int n, int v) {
  int lo = 0, hi = n;
  while (lo < hi) { int mid = (lo + hi) >> 1; if (b[mid] < v) lo = mid + 1; else hi = mid; }
  return lo;
}

__global__ __launch_bounds__(1024)
void gn_stats_k(const float* __restrict__ z, const int* __restrict__ batch, int n,
                const float* __restrict__ mss,
                float* __restrict__ meanms, float* __restrict__ rstd) {
  const int g = blockIdx.x;
  const int tid = threadIdx.x;
  const int ry = tid >> 7, c = tid & 127;
  __shared__ int lohi[2];
  __shared__ float red[8][128];
  __shared__ float mnsh[128];
  if (tid == 0) { lohi[0] = lbound(batch, n, g); lohi[1] = lbound(batch, n, g + 1); }
  __syncthreads();
  const int lo = lohi[0], hi = lohi[1];
  const float cnt = (float)max(hi - lo, 1);

  float s = 0.f;
  for (int r = lo + ry; r < hi; r += 8) s += z[(size_t)r * 128 + c];
  red[ry][c] = s;
  __syncthreads();
  if (ry == 0) {
    float t = 0.f;
    #pragma unroll
    for (int j = 0; j < 8; ++j) t += red[j][c];
    mnsh[c] = (t / cnt) * mss[c];
  }
  __syncthreads();
  const float mn = mnsh[c];

  float m2 = 0.f;
  for (int r = lo + ry; r < hi; r += 8) {
    float o = z[(size_t)r * 128 + c] - mn;
    m2 += o * o;
  }
  red[ry][c] = m2;
  __syncthreads();
  if (ry == 0) {
    float t = 0.f;
    #pragma unroll
    for (int j = 0; j < 8; ++j) t += red[j][c];
    meanms[g * 128 + c] = mn;
    rstd[g * 128 + c] = rsqrtf(t / cnt + EPSV);
  }
}

__global__ void gn_apply_k(const float* __restrict__ z, const int* __restrict__ batch,
                           const float* __restrict__ w, const float* __restrict__ b,
                           const float* __restrict__ meanms, const float* __restrict__ rstd,
                           float* __restrict__ out, int n) {
  int i = blockIdx.x * blockDim.x + threadIdx.x;
  if (i >= n * 32) return;
  const int r = i >> 5;
  const int c = (i & 31) * 4;
  const int g = batch[r];
  float4 zv = *reinterpret_cast<const float4*>(z + (size_t)r * 128 + c);
  float4 mm = *reinterpret_cast<const float4*>(meanms + g * 128 + c);
  float4 rs = *reinterpret_cast<const float4*>(rstd + g * 128 + c);
  float4 wv = *reinterpret_cast<const float4*>(w + c);
  float4 bv = *reinterpret_cast<const float4*>(b + c);
  float4 o;
  o.x = wv.x * (zv.x - mm.x) * rs.x + bv.x;
  o.y = wv.y * (zv.y - mm.y) * rs.y + bv.y;
  o.z = wv.z * (zv.z - mm.z) * rs.z + bv.z;
  o.w = wv.w * (zv.w - mm.w) * rs.w + bv.w;
  *reinterpret_cast<float4*>(out + (size_t)r * 128 + c) = o;
}

// ---------------------------------------------------------------------------
extern "C" void kernel_launch(void* const* d_in, const int* in_sizes, int n_in,
                              void* d_out, int out_size, void* d_ws, size_t ws_size,
                              hipStream_t stream) {
  const float* x0   = (const float*)d_in[0];
  const float* x1   = (const float*)d_in[1];
  const float* x2   = (const float*)d_in[2];
  const float* L0   = (const float*)d_in[3];
  const float* L1   = (const float*)d_in[4];
  const float* L2   = (const float*)d_in[5];
  const float* inc1 = (const float*)d_in[6];
  const float* inc2 = (const float*)d_in[7];
  const float* W0   = (const float*)d_in[8];
  const float* W1   = (const float*)d_in[9];
  const float* W2   = (const float*)d_in[10];
  const float* Wc1  = (const float*)d_in[11];
  const float* Wc2  = (const float*)d_in[12];
  const float* g1w  = (const float*)d_in[13];
  const float* g1b  = (const float*)d_in[14];
  const float* g1m  = (const float*)d_in[15];
  const float* g2w  = (const float*)d_in[16];
  const float* g2b  = (const float*)d_in[17];
  const float* g2m  = (const float*)d_in[18];
  const int*   bat0 = (const int*)d_in[19];
  const int*   bat1 = (const int*)d_in[20];

  const int N0 = 4096, N1 = 8192, N2 = 6144;

  float* ws = (float*)d_ws;
  size_t off = 0;
  auto alloc = [&](size_t nf) { float* p = ws + off; off += (nf + 63) & ~(size_t)63; return p; };
  float* inv0   = alloc(N0);
  float* inv1   = alloc(N1);
  float* inv2   = alloc(N2);
  u16*   tT0    = (u16*)alloc((size_t)N0 * 64);
  u16*   tT1    = (u16*)alloc((size_t)N1 * 64);
  u16*   tT2    = (u16*)alloc((size_t)N2 * 64);
  float* h0     = alloc((size_t)N0 * 128);
  float* h1     = alloc((size_t)N1 * 128);
  float* z      = alloc((size_t)N1 * 128);
  float* meanms = alloc(64 * 128);
  float* rstd   = alloc(64 * 128);
  u16*   part   = (u16*)alloc((size_t)7602208);        // 15.2M u16 partials

  u16* part1 = part;                                    // S=8, n=8192
  u16* part2 = part1 + (size_t)8 * N1 * 128;            // S=6, n=6144
  u16* part0 = part2 + (size_t)6 * N2 * 128;            // S=4, n=4096

  float* out0 = (float*)d_out;
  float* out1 = out0 + (size_t)N0 * 128;
  float* out2 = out1 + (size_t)N1 * 128;

  // ===== batched L-pipeline: h_i = sigmoid(inv*(L @ (inv*(x@W)))) =====
  rowsum_all_k<<<(N0 + N1 + N2) / 4, 256, 0, stream>>>(L0, L1, L2, inv0, inv1, inv2);
  gsmall_all_k<<<(N0 + N1 + N2) / 32, 256, 0, stream>>>(x1, W1, tT1, inv1,
                                                        x2, W2, tT2, inv2,
                                                        x0, W0, tT0, inv0);
  mfma_dma32_all_k<<<1856, 256, 0, stream>>>(L1, tT1, part1, L2, tT2, part2, L0, tT0, part0);
  reduce_sigmoid_all_k<<<(N0 + N1 + N2) * 16 / 256, 256, 0, stream>>>(
      part1, part2, part0, inv1, inv2, inv0, h1, out2, h0);

  // ===== x1_out = graphnorm(h1 + inc2 @ (out2 @ Wc1)) =====
  gemm_small_k<<<N2 / 32, 256, 0, stream>>>(out2, Wc1, tT2, N2);
  mfma_gemm_reg_k<<<dim3(N1 / 64, 4), 256, 0, stream>>>(inc2, N2, tT2, N2, part, N1, N2, 1536);
  reduce_add_k<<<N1 * 16 / 256, 256, 0, stream>>>(part, 4, (size_t)N1 * 128, h1, z, N1);
  gn_stats_k<<<64, 1024, 0, stream>>>(z, bat1, N1, g1m, meanms, rstd);
  gn_apply_k<<<N1 * 32 / 256, 256, 0, stream>>>(z, bat1, g1w, g1b, meanms, rstd, out1, N1);

  // ===== x0_out = graphnorm(h0 + inc1 @ (x1_out @ Wc2)) =====
  gemm_small_k<<<N1 / 32, 256, 0, stream>>>(out1, Wc2, tT1, N1);
  mfma_gemm_reg_k<<<dim3(N0 / 64, 8), 256, 0, stream>>>(inc1, N1, tT1, N1, part, N0, N1, 1024);
  reduce_add_k<<<N0 * 16 / 256, 256, 0, stream>>>(part, 8, (size_t)N0 * 128, h0, z, N0);
  gn_stats_k<<<64, 1024, 0, stream>>>(z, bat0, N0, g2m, meanms, rstd);
  gn_apply_k<<<N0 * 32 / 256, 256, 0, stream>>>(z, bat0, g2w, g2b, meanms, rstd, out0, N0);
}

// Round 13
// 377.665 us; speedup vs baseline: 1.0309x; 1.0309x over previous
//
#include <hip/hip_runtime.h>
#include <math.h>

// ---------------------------------------------------------------------------
// SCN layer, round 13 = round 8 (best, 378.8us) with ONE change: the batched
// L-GEMM's level packing flipped to lev0 -> lev2 -> lev1 so the GEMM reads
// Lh0/Lh2 (109MB, L3-resident from the rowsum pass that just wrote them)
// before streaming the cold 134MB Lh1. r11 counters proved L3 absorbs ~50%
// of L-path re-reads even with the wrong order; this aims the reuse.
// ---------------------------------------------------------------------------

#define EPSV 1e-5f

typedef unsigned short u16;
typedef u16 u16x4 __attribute__((ext_vector_type(4)));
typedef u16 u16x8 __attribute__((ext_vector_type(8)));
typedef float f32x4 __attribute__((ext_vector_type(4)));
typedef _Float16 f16x4 __attribute__((ext_vector_type(4)));
typedef _Float16 f16x8 __attribute__((ext_vector_type(8)));

__device__ inline u16 f2h(float f) {
  union { _Float16 h; u16 u; } c;
  c.h = (_Float16)f;
  return c.u;
}
__device__ inline float h2f(u16 u) {
  union { u16 u; _Float16 h; } c;
  c.u = u;
  return (float)c.h;
}

// ---------------- batched rowsum -> inv + fp16 copy of L (all 3 levels) ----------------
// Block order L1 -> L2 -> L0: ends with Lh0/L0 (hottest) and Lh2/L2 (warm) in L3.
__global__ __launch_bounds__(256)
void rowsum_all_k(const float* __restrict__ L0, const float* __restrict__ L1,
                  const float* __restrict__ L2,
                  float* __restrict__ inv0, float* __restrict__ inv1, float* __restrict__ inv2,
                  u16* __restrict__ Lh0, u16* __restrict__ Lh1, u16* __restrict__ Lh2) {
  const int b = blockIdx.x;
  const float* L; float* inv; u16* Lh; int m, r;
  if (b < 8192)       { L = L1; inv = inv1; Lh = Lh1; m = 8192; r = b; }
  else if (b < 14336) { L = L2; inv = inv2; Lh = Lh2; m = 6144; r = b - 8192; }
  else                { L = L0; inv = inv0; Lh = Lh0; m = 4096; r = b - 14336; }

  const float* row = L + (size_t)r * m;
  u16* orow = Lh + (size_t)r * m;
  const int tid = threadIdx.x;
  float s = 0.f;
  for (int c = tid * 4; c < m; c += 256 * 4) {
    float4 v = *reinterpret_cast<const float4*>(row + c);
    s += fabsf(v.x) + fabsf(v.y) + fabsf(v.z) + fabsf(v.w);
    u16x4 h;
    h[0] = f2h(v.x); h[1] = f2h(v.y); h[2] = f2h(v.z); h[3] = f2h(v.w);
    *reinterpret_cast<u16x4*>(orow + c) = h;
  }
  #pragma unroll
  for (int o = 32; o > 0; o >>= 1) s += __shfl_down(s, o, 64);
  __shared__ float red[4];
  if ((tid & 63) == 0) red[tid >> 6] = s;
  __syncthreads();
  if (tid == 0) {
    float d = red[0] + red[1] + red[2] + red[3];
    inv[r] = (d != 0.f) ? rsqrtf(d) : 0.f;
  }
}

// ---------------- batched small GEMM (3 levels): tT[c][r] = fp16((x@W)[r][c]*inv[r]) ----
__global__ __launch_bounds__(256)
void gsmall_all_k(const float* __restrict__ x1, const float* __restrict__ W1,
                  u16* __restrict__ tT1, const float* __restrict__ inv1,
                  const float* __restrict__ x2, const float* __restrict__ W2,
                  u16* __restrict__ tT2, const float* __restrict__ inv2,
                  const float* __restrict__ x0, const float* __restrict__ W0,
                  u16* __restrict__ tT0, const float* __restrict__ inv0)
{
  const int b = blockIdx.x;
  const float *A, *B, *scale; u16* outT; int ldo, rowblk;
  if (b < 256)      { A = x1; B = W1; outT = tT1; scale = inv1; ldo = 8192; rowblk = b * 32; }
  else if (b < 448) { A = x2; B = W2; outT = tT2; scale = inv2; ldo = 6144; rowblk = (b - 256) * 32; }
  else              { A = x0; B = W0; outT = tT0; scale = inv0; ldo = 4096; rowblk = (b - 448) * 32; }

  __shared__ float As[32][36];
  __shared__ float Bs[32][128];
  const int tid = threadIdx.x;

  float acc[4][4];
  #pragma unroll
  for (int i = 0; i < 4; ++i)
    #pragma unroll
    for (int j = 0; j < 4; ++j) acc[i][j] = 0.f;

  const int a_row = tid >> 3, a_col = (tid & 7) * 4;
  const int b_row = tid >> 5, b_col = (tid & 31) * 4;
  const int row0 = (tid >> 5) * 4, col0 = (tid & 31) * 4;

  for (int kk = 0; kk < 128; kk += 32) {
    *reinterpret_cast<float4*>(&As[a_row][a_col]) =
        *reinterpret_cast<const float4*>(A + (size_t)(rowblk + a_row) * 128 + kk + a_col);
    #pragma unroll
    for (int i = 0; i < 4; ++i) {
      int r = b_row + i * 8;
      *reinterpret_cast<float4*>(&Bs[r][b_col]) =
          *reinterpret_cast<const float4*>(B + (size_t)(kk + r) * 128 + b_col);
    }
    __syncthreads();
    #pragma unroll
    for (int k = 0; k < 32; ++k) {
      float4 bb = *reinterpret_cast<const float4*>(&Bs[k][col0]);
      #pragma unroll
      for (int i = 0; i < 4; ++i) {
        float a = As[row0 + i][k];
        acc[i][0] = fmaf(a, bb.x, acc[i][0]);
        acc[i][1] = fmaf(a, bb.y, acc[i][1]);
        acc[i][2] = fmaf(a, bb.z, acc[i][2]);
        acc[i][3] = fmaf(a, bb.w, acc[i][3]);
      }
    }
    __syncthreads();
  }

  const int rb = rowblk + row0;
  float sc[4];
  #pragma unroll
  for (int i = 0; i < 4; ++i) sc[i] = scale[rb + i];
  #pragma unroll
  for (int j = 0; j < 4; ++j) {
    u16x4 p;
    #pragma unroll
    for (int i = 0; i < 4; ++i) p[i] = f2h(acc[i][j] * sc[i]);
    *reinterpret_cast<u16x4*>(outT + (size_t)(col0 + j) * ldo + rb) = p;
  }
}

// ---------------- small GEMM (single level, no scale) for inc prepasses ----------------
__global__ __launch_bounds__(256)
void gemm_small_k(const float* __restrict__ A, const float* __restrict__ B,
                  u16* __restrict__ outT, int ldo)
{
  __shared__ float As[32][36];
  __shared__ float Bs[32][128];
  const int tid = threadIdx.x;
  const int rowblk = blockIdx.x * 32;

  float acc[4][4];
  #pragma unroll
  for (int i = 0; i < 4; ++i)
    #pragma unroll
    for (int j = 0; j < 4; ++j) acc[i][j] = 0.f;

  const int a_row = tid >> 3, a_col = (tid & 7) * 4;
  const int b_row = tid >> 5, b_col = (tid & 31) * 4;
  const int row0 = (tid >> 5) * 4, col0 = (tid & 31) * 4;

  for (int kk = 0; kk < 128; kk += 32) {
    *reinterpret_cast<float4*>(&As[a_row][a_col]) =
        *reinterpret_cast<const float4*>(A + (size_t)(rowblk + a_row) * 128 + kk + a_col);
    #pragma unroll
    for (int i = 0; i < 4; ++i) {
      int r = b_row + i * 8;
      *reinterpret_cast<float4*>(&Bs[r][b_col]) =
          *reinterpret_cast<const float4*>(B + (size_t)(kk + r) * 128 + b_col);
    }
    __syncthreads();
    #pragma unroll
    for (int k = 0; k < 32; ++k) {
      float4 bb = *reinterpret_cast<const float4*>(&Bs[k][col0]);
      #pragma unroll
      for (int i = 0; i < 4; ++i) {
        float a = As[row0 + i][k];
        acc[i][0] = fmaf(a, bb.x, acc[i][0]);
        acc[i][1] = fmaf(a, bb.y, acc[i][1]);
        acc[i][2] = fmaf(a, bb.z, acc[i][2]);
        acc[i][3] = fmaf(a, bb.w, acc[i][3]);
      }
    }
    __syncthreads();
  }

  const int rb = rowblk + row0;
  #pragma unroll
  for (int j = 0; j < 4; ++j) {
    u16x4 p;
    #pragma unroll
    for (int i = 0; i < 4; ++i) p[i] = f2h(acc[i][j]);
    *reinterpret_cast<u16x4*>(outT + (size_t)(col0 + j) * ldo + rb) = p;
  }
}

// ---------------- batched MFMA GEMM, DMA-staged, counted vmcnt ----------------
// L3-aware level order: b<256 lev0(4096,S=4) [hot], <832 lev2(6144,S=6) [warm],
// else lev1(8192,S=8) [cold stream]. kchunk=1024 -> nsteps=16. 64-row tile.
__global__ __launch_bounds__(256, 3)
void mfma_dma_all_k(const u16* __restrict__ Lh1, const u16* __restrict__ tT1, u16* __restrict__ part1,
                    const u16* __restrict__ Lh2, const u16* __restrict__ tT2, u16* __restrict__ part2,
                    const u16* __restrict__ Lh0, const u16* __restrict__ tT0, u16* __restrict__ part0)
{
  __shared__ __align__(16) u16 smem[2][192 * 64];    // per buf: rows 0..63 A | 64..191 B

  const int tid = threadIdx.x;
  const int b = blockIdx.x;
  const u16 *Ah, *Bt; u16* pbase; int n, K, rb, sp;
  if (b < 256)      { Ah = Lh0; Bt = tT0; pbase = part0; n = 4096; K = 4096; rb = b & 63; sp = b >> 6; }
  else if (b < 832) { int t = b - 256; Ah = Lh2; Bt = tT2; pbase = part2; n = 6144; K = 6144; rb = t % 96; sp = t / 96; }
  else              { int t = b - 832; Ah = Lh1; Bt = tT1; pbase = part1; n = 8192; K = 8192; rb = t & 127; sp = t >> 7; }
  const int rowblk = rb * 64;
  const int k0 = sp * 1024;
  const int nsteps = 16;

  const int l = tid & 63, w = tid >> 6;
  const int lr8 = l >> 3;
  const int sc = (l & 7) ^ lr8;                      // pre-swizzled source chunk
  const u16* gAl = Ah + (size_t)(rowblk + lr8) * K + k0 + sc * 8;
  const u16* gBl = Bt + (size_t)lr8 * K + k0 + sc * 8;

#define STAGE(BUF, S)                                                          \
  {                                                                            \
    _Pragma("unroll")                                                          \
    for (int p = 0; p < 2; ++p) {                                              \
      const int rbase = (w + p * 4) * 8;                                       \
      __builtin_amdgcn_global_load_lds(                                        \
          (const __attribute__((address_space(1))) void*)(gAl + (size_t)rbase * K + (S) * 64), \
          (__attribute__((address_space(3))) void*)(&smem[BUF][rbase * 64]),   \
          16, 0, 0);                                                           \
    }                                                                          \
    _Pragma("unroll")                                                          \
    for (int p = 0; p < 4; ++p) {                                              \
      const int rbase = (w + p * 4) * 8;                                       \
      __builtin_amdgcn_global_load_lds(                                        \
          (const __attribute__((address_space(1))) void*)(gBl + (size_t)rbase * K + (S) * 64), \
          (__attribute__((address_space(3))) void*)(&smem[BUF][(64 + rbase) * 64]), \
          16, 0, 0);                                                           \
    }                                                                          \
  }

  const int wr = (w >> 1) * 32, wc = (w & 1) * 64;
  const int lrow = l & 15, lks = l >> 4, lsw = l & 7;

  f32x4 acc[2][4];
  #pragma unroll
  for (int mi = 0; mi < 2; ++mi)
    #pragma unroll
    for (int ni = 0; ni < 4; ++ni) acc[mi][ni] = (f32x4){0.f, 0.f, 0.f, 0.f};

  STAGE(0, 0);

  int cur = 0;
  for (int s = 0; s < nsteps; ++s) {
    if (s + 1 < nsteps) {
      STAGE(cur ^ 1, s + 1);                          // 6 more loads in flight
      asm volatile("s_waitcnt vmcnt(6)" ::: "memory"); // stage(s) done; stage(s+1) flies
    } else {
      asm volatile("s_waitcnt vmcnt(0)" ::: "memory");
    }
    asm volatile("s_barrier" ::: "memory");           // all waves: buf[cur] populated
    const char* sA = (const char*)&smem[cur][0];
    const char* sB = (const char*)&smem[cur][64 * 64];
    #pragma unroll
    for (int ks = 0; ks < 2; ++ks) {
      const int fo = ((((ks << 2) | lks) ^ lsw) << 4);
      f16x8 bf[4];
      #pragma unroll
      for (int ni = 0; ni < 4; ++ni)
        bf[ni] = *reinterpret_cast<const f16x8*>(sB + ((wc + ni * 16 + lrow) << 7) + fo);
      #pragma unroll
      for (int mi = 0; mi < 2; ++mi) {
        f16x8 af = *reinterpret_cast<const f16x8*>(sA + ((wr + mi * 16 + lrow) << 7) + fo);
        #pragma unroll
        for (int ni = 0; ni < 4; ++ni)
          acc[mi][ni] = __builtin_amdgcn_mfma_f32_16x16x32_f16(af, bf[ni], acc[mi][ni], 0, 0, 0);
      }
    }
    asm volatile("s_barrier" ::: "memory");           // buf[cur] free for overwrite
    cur ^= 1;
  }
#undef STAGE

  u16* o = pbase + (size_t)sp * n * 128;
  #pragma unroll
  for (int mi = 0; mi < 2; ++mi)
    #pragma unroll
    for (int ni = 0; ni < 4; ++ni) {
      const int gr = rowblk + wr + mi * 16 + lks * 4;
      const int gc = wc + ni * 16 + lrow;
      f32x4 v = acc[mi][ni];
      #pragma unroll
      for (int q = 0; q < 4; ++q) o[(size_t)(gr + q) * 128 + gc] = f2h(v[q]);
    }
}

// ---------------- MFMA GEMM, reg-staged (A fp32), 64-row tile (inc GEMMs) ----------------
#define LDS_A 0
#define LDS_B 8192
__global__ __launch_bounds__(256, 4)
void mfma_gemm_reg_k(const float* __restrict__ A, int lda,
                     const u16* __restrict__ Bt, int ldb,
                     u16* __restrict__ part,
                     int n, int K, int kchunk)
{
  __shared__ __align__(16) char smem[24576];

  const int tid = threadIdx.x;
  const int rowblk = blockIdx.x * 64;
  const int k0 = blockIdx.y * kchunk;
  const int nsteps = kchunk >> 6;

  const int ar = tid >> 4, acol = (tid & 15) * 4;
  const float* gA = A + (size_t)(rowblk + ar) * lda + k0 + acol;
  const int awb = (ar << 7) + (((((tid & 15) >> 1) ^ (ar & 7)) << 4)) + (tid & 1) * 8;
  const int br = tid >> 3, bc = tid & 7;
  const u16* gB = Bt + (size_t)br * ldb + k0 + bc * 8;
  const int bwb = (br << 7) + (((bc ^ (br & 7)) << 4));

  const int l = tid & 63, w = tid >> 6;
  const int wr = (w >> 1) * 32, wc = (w & 1) * 64;
  const int lrow = l & 15, lks = l >> 4, lsw = l & 7;

  f32x4 acc[2][4];
  #pragma unroll
  for (int mi = 0; mi < 2; ++mi)
    #pragma unroll
    for (int ni = 0; ni < 4; ++ni) acc[mi][ni] = (f32x4){0.f, 0.f, 0.f, 0.f};

  f32x4 ra[4]; u16x8 rbv[4];

#define LOADG(S)                                                              \
  {                                                                           \
    const float* pA = gA + (size_t)(S) * 64;                                  \
    const u16*   pB = gB + (size_t)(S) * 64;                                  \
    _Pragma("unroll")                                                         \
    for (int p = 0; p < 4; ++p) ra[p] = *reinterpret_cast<const f32x4*>(pA + (size_t)p * 16 * lda); \
    _Pragma("unroll")                                                         \
    for (int p = 0; p < 4; ++p) rbv[p] = *reinterpret_cast<const u16x8*>(pB + (size_t)p * 32 * ldb); \
  }

#define STORE_LDS()                                                           \
  {                                                                           \
    _Pragma("unroll")                                                         \
    for (int p = 0; p < 4; ++p) {                                             \
      f16x4 h;                                                                \
      h[0] = (_Float16)ra[p][0]; h[1] = (_Float16)ra[p][1];                   \
      h[2] = (_Float16)ra[p][2]; h[3] = (_Float16)ra[p][3];                   \
      *reinterpret_cast<f16x4*>(smem + LDS_A + awb + p * (16 << 7)) = h;      \
    }                                                                         \
    _Pragma("unroll")                                                         \
    for (int p = 0; p < 4; ++p)                                               \
      *reinterpret_cast<u16x8*>(smem + LDS_B + bwb + p * (32 << 7)) = rbv[p]; \
  }

  LOADG(0);
  STORE_LDS();
  __syncthreads();

  for (int s = 0; s < nsteps; ++s) {
    if (s + 1 < nsteps) LOADG(s + 1);
    #pragma unroll
    for (int ks = 0; ks < 2; ++ks) {
      const int fo = ((((ks << 2) | lks) ^ lsw) << 4);
      f16x8 bf[4];
      #pragma unroll
      for (int ni = 0; ni < 4; ++ni)
        bf[ni] = *reinterpret_cast<const f16x8*>(
            smem + LDS_B + ((wc + ni * 16 + lrow) << 7) + fo);
      #pragma unroll
      for (int mi = 0; mi < 2; ++mi) {
        f16x8 af = *reinterpret_cast<const f16x8*>(
            smem + LDS_A + ((wr + mi * 16 + lrow) << 7) + fo);
        #pragma unroll
        for (int ni = 0; ni < 4; ++ni)
          acc[mi][ni] = __builtin_amdgcn_mfma_f32_16x16x32_f16(af, bf[ni], acc[mi][ni], 0, 0, 0);
      }
    }
    __syncthreads();
    if (s + 1 < nsteps) STORE_LDS();
    __syncthreads();
  }

  u16* o = part + (size_t)blockIdx.y * n * 128;
  #pragma unroll
  for (int mi = 0; mi < 2; ++mi)
    #pragma unroll
    for (int ni = 0; ni < 4; ++ni) {
      const int gr = rowblk + wr + mi * 16 + lks * 4;
      const int gc = wc + ni * 16 + lrow;
      f32x4 v = acc[mi][ni];
      #pragma unroll
      for (int q = 0; q < 4; ++q) o[(size_t)(gr + q) * 128 + gc] = f2h(v[q]);
    }
#undef LOADG
#undef STORE_LDS
}

// ---------------- batched split-K reduce + sigmoid (3 levels) ----------------
__global__ void reduce_sigmoid_all_k(const u16* __restrict__ part1, const u16* __restrict__ part2,
                                     const u16* __restrict__ part0,
                                     const float* __restrict__ inv1, const float* __restrict__ inv2,
                                     const float* __restrict__ inv0,
                                     float* __restrict__ h1, float* __restrict__ out2,
                                     float* __restrict__ h0)
{
  const int i = blockIdx.x * 256 + threadIdx.x;      // u16x8 chunk; 16 per row
  const int row = i >> 4;
  const u16* pb; const float* inv; float* out; int S, lrow; size_t stride;
  if (row < 8192)       { pb = part1; inv = inv1; out = h1;   S = 8; lrow = row;         stride = (size_t)8192 * 128; }
  else if (row < 14336) { pb = part2; inv = inv2; out = out2; S = 6; lrow = row - 8192;  stride = (size_t)6144 * 128; }
  else                  { pb = part0; inv = inv0; out = h0;   S = 4; lrow = row - 14336; stride = (size_t)4096 * 128; }

  const size_t off = (size_t)lrow * 128 + (i & 15) * 8;
  float s[8] = {0.f, 0.f, 0.f, 0.f, 0.f, 0.f, 0.f, 0.f};
  for (int sp = 0; sp < S; ++sp) {
    u16x8 v = *reinterpret_cast<const u16x8*>(pb + (size_t)sp * stride + off);
    #pragma unroll
    for (int j = 0; j < 8; ++j) s[j] += h2f(v[j]);
  }
  const float iv = inv[lrow];
  float4 o0, o1;
  o0.x = 1.f / (1.f + expf(-iv * s[0]));
  o0.y = 1.f / (1.f + expf(-iv * s[1]));
  o0.z = 1.f / (1.f + expf(-iv * s[2]));
  o0.w = 1.f / (1.f + expf(-iv * s[3]));
  o1.x = 1.f / (1.f + expf(-iv * s[4]));
  o1.y = 1.f / (1.f + expf(-iv * s[5]));
  o1.z = 1.f / (1.f + expf(-iv * s[6]));
  o1.w = 1.f / (1.f + expf(-iv * s[7]));
  *reinterpret_cast<float4*>(out + off) = o0;
  *reinterpret_cast<float4*>(out + off + 4) = o1;
}

// ---------------- split-K reduce + add (fp16 partials) ----------------
__global__ void reduce_add_k(const u16* __restrict__ part, int S, size_t stride,
                             const float* __restrict__ h, float* __restrict__ z, int n) {
  int i = blockIdx.x * blockDim.x + threadIdx.x;
  if (i >= n * 16) return;
  size_t off = (size_t)i * 8;
  float s[8] = {0.f, 0.f, 0.f, 0.f, 0.f, 0.f, 0.f, 0.f};
  for (int sp = 0; sp < S; ++sp) {
    u16x8 v = *reinterpret_cast<const u16x8*>(part + (size_t)sp * stride + off);
    #pragma unroll
    for (int j = 0; j < 8; ++j) s[j] += h2f(v[j]);
  }
  float4 h0 = *reinterpret_cast<const float4*>(h + off);
  float4 h1 = *reinterpret_cast<const float4*>(h + off + 4);
  float4 o0 = make_float4(s[0] + h0.x, s[1] + h0.y, s[2] + h0.z, s[3] + h0.w);
  float4 o1 = make_float4(s[4] + h1.x, s[5] + h1.y, s[6] + h1.z, s[7] + h1.w);
  *reinterpret_cast<float4*>(z + off) = o0;
  *reinterpret_cast<float4*>(z + off + 4) = o1;
}

// ---------------- graph norm ----------------
__device__ inline int lbound(const int* __restrict__ b, int n, int v) {
  int lo = 0, hi = n;
  while (lo < hi) { int mid = (lo + hi) >> 1; if (b[mid] < v) lo = mid + 1; else hi = mid; }
  return lo;
}

__global__ __launch_bounds__(1024)
void gn_stats_k(const float* __restrict__ z, const int* __restrict__ batch, int n,
                const float* __restrict__ mss,
                float* __restrict__ meanms, float* __restrict__ rstd) {
  const int g = blockIdx.x;
  const int tid = threadIdx.x;
  const int ry = tid >> 7, c = tid & 127;
  __shared__ int lohi[2];
  __shared__ float red[8][128];
  __shared__ float mnsh[128];
  if (tid == 0) { lohi[0] = lbound(batch, n, g); lohi[1] = lbound(batch, n, g + 1); }
  __syncthreads();
  const int lo = lohi[0], hi = lohi[1];
  const float cnt = (float)max(hi - lo, 1);

  float s = 0.f;
  for (int r = lo + ry; r < hi; r += 8) s += z[(size_t)r * 128 + c];
  red[ry][c] = s;
  __syncthreads();
  if (ry == 0) {
    float t = 0.f;
    #pragma unroll
    for (int j = 0; j < 8; ++j) t += red[j][c];
    mnsh[c] = (t / cnt) * mss[c];
  }
  __syncthreads();
  const float mn = mnsh[c];

  float m2 = 0.f;
  for (int r = lo + ry; r < hi; r += 8) {
    float o = z[(size_t)r * 128 + c] - mn;
    m2 += o * o;
  }
  red[ry][c] = m2;
  __syncthreads();
  if (ry == 0) {
    float t = 0.f;
    #pragma unroll
    for (int j = 0; j < 8; ++j) t += red[j][c];
    meanms[g * 128 + c] = mn;
    rstd[g * 128 + c] = rsqrtf(t / cnt + EPSV);
  }
}

__global__ void gn_apply_k(const float* __restrict__ z, const int* __restrict__ batch,
                           const float* __restrict__ w, const float* __restrict__ b,
                           const float* __restrict__ meanms, const float* __restrict__ rstd,
                           float* __restrict__ out, int n) {
  int i = blockIdx.x * blockDim.x + threadIdx.x;
  if (i >= n * 32) return;
  const int r = i >> 5;
  const int c = (i & 31) * 4;
  const int g = batch[r];
  float4 zv = *reinterpret_cast<const float4*>(z + (size_t)r * 128 + c);
  float4 mm = *reinterpret_cast<const float4*>(meanms + g * 128 + c);
  float4 rs = *reinterpret_cast<const float4*>(rstd + g * 128 + c);
  float4 wv = *reinterpret_cast<const float4*>(w + c);
  float4 bv = *reinterpret_cast<const float4*>(b + c);
  float4 o;
  o.x = wv.x * (zv.x - mm.x) * rs.x + bv.x;
  o.y = wv.y * (zv.y - mm.y) * rs.y + bv.y;
  o.z = wv.z * (zv.z - mm.z) * rs.z + bv.z;
  o.w = wv.w * (zv.w - mm.w) * rs.w + bv.w;
  *reinterpret_cast<float4*>(out + (size_t)r * 128 + c) = o;
}

// ---------------------------------------------------------------------------
extern "C" void kernel_launch(void* const* d_in, const int* in_sizes, int n_in,
                              void* d_out, int out_size, void* d_ws, size_t ws_size,
                              hipStream_t stream) {
  const float* x0   = (const float*)d_in[0];
  const float* x1   = (const float*)d_in[1];
  const float* x2   = (const float*)d_in[2];
  const float* L0   = (const float*)d_in[3];
  const float* L1   = (const float*)d_in[4];
  const float* L2   = (const float*)d_in[5];
  const float* inc1 = (const float*)d_in[6];
  const float* inc2 = (const float*)d_in[7];
  const float* W0   = (const float*)d_in[8];
  const float* W1   = (const float*)d_in[9];
  const float* W2   = (const float*)d_in[10];
  const float* Wc1  = (const float*)d_in[11];
  const float* Wc2  = (const float*)d_in[12];
  const float* g1w  = (const float*)d_in[13];
  const float* g1b  = (const float*)d_in[14];
  const float* g1m  = (const float*)d_in[15];
  const float* g2w  = (const float*)d_in[16];
  const float* g2b  = (const float*)d_in[17];
  const float* g2m  = (const float*)d_in[18];
  const int*   bat0 = (const int*)d_in[19];
  const int*   bat1 = (const int*)d_in[20];

  const int N0 = 4096, N1 = 8192, N2 = 6144;

  float* ws = (float*)d_ws;
  size_t off = 0;
  auto alloc = [&](size_t nf) { float* p = ws + off; off += (nf + 63) & ~(size_t)63; return p; };
  float* inv0   = alloc(N0);
  float* inv1   = alloc(N1);
  float* inv2   = alloc(N2);
  u16*   tT0    = (u16*)alloc((size_t)N0 * 64);
  u16*   tT1    = (u16*)alloc((size_t)N1 * 64);
  u16*   tT2    = (u16*)alloc((size_t)N2 * 64);
  u16*   Lh0    = (u16*)alloc((size_t)N0 * N0 / 2);
  u16*   Lh1    = (u16*)alloc((size_t)N1 * N1 / 2);
  u16*   Lh2    = (u16*)alloc((size_t)N2 * N2 / 2);
  float* h0     = alloc((size_t)N0 * 128);
  float* h1     = alloc((size_t)N1 * 128);
  float* z      = alloc((size_t)N1 * 128);
  float* meanms = alloc(64 * 128);
  float* rstd   = alloc(64 * 128);
  u16*   part   = (u16*)alloc((size_t)7602208);        // 15.2M u16 partials

  u16* part1 = part;                                    // S=8, n=8192
  u16* part2 = part1 + (size_t)8 * N1 * 128;            // S=6, n=6144
  u16* part0 = part2 + (size_t)6 * N2 * 128;            // S=4, n=4096

  float* out0 = (float*)d_out;
  float* out1 = out0 + (size_t)N0 * 128;
  float* out2 = out1 + (size_t)N1 * 128;

  // ===== batched L-pipeline: h_i = sigmoid(inv*(L @ (inv*(x@W)))) =====
  rowsum_all_k<<<N0 + N1 + N2, 256, 0, stream>>>(L0, L1, L2, inv0, inv1, inv2, Lh0, Lh1, Lh2);
  gsmall_all_k<<<(N0 + N1 + N2) / 32, 256, 0, stream>>>(x1, W1, tT1, inv1,
                                                        x2, W2, tT2, inv2,
                                                        x0, W0, tT0, inv0);
  mfma_dma_all_k<<<1856, 256, 0, stream>>>(Lh1, tT1, part1, Lh2, tT2, part2, Lh0, tT0, part0);
  reduce_sigmoid_all_k<<<(N0 + N1 + N2) * 16 / 256, 256, 0, stream>>>(
      part1, part2, part0, inv1, inv2, inv0, h1, out2, h0);

  // ===== x1_out = graphnorm(h1 + inc2 @ (out2 @ Wc1)) =====
  gemm_small_k<<<N2 / 32, 256, 0, stream>>>(out2, Wc1, tT2, N2);
  mfma_gemm_reg_k<<<dim3(N1 / 64, 4), 256, 0, stream>>>(inc2, N2, tT2, N2, part, N1, N2, 1536);
  reduce_add_k<<<N1 * 16 / 256, 256, 0, stream>>>(part, 4, (size_t)N1 * 128, h1, z, N1);
  gn_stats_k<<<64, 1024, 0, stream>>>(z, bat1, N1, g1m, meanms, rstd);
  gn_apply_k<<<N1 * 32 / 256, 256, 0, stream>>>(z, bat1, g1w, g1b, meanms, rstd, out1, N1);

  // ===== x0_out = graphnorm(h0 + inc1 @ (x1_out @ Wc2)) =====
  gemm_small_k<<<N1 / 32, 256, 0, stream>>>(out1, Wc2, tT1, N1);
  mfma_gemm_reg_k<<<dim3(N0 / 64, 8), 256, 0, stream>>>(inc1, N1, tT1, N1, part, N0, N1, 1024);
  reduce_add_k<<<N0 * 16 / 256, 256, 0, stream>>>(part, 8, (size_t)N0 * 128, h0, z, N0);
  gn_stats_k<<<64, 1024, 0, stream>>>(z, bat0, N0, g2m, meanms, rstd);
  gn_apply_k<<<N0 * 32 / 256, 256, 0, stream>>>(z, bat0, g2w, g2b, meanms, rstd, out0, N0);
}